// Round 2
// baseline (419.816 us; speedup 1.0000x reference)
//
#include <hip/hip_runtime.h>

#define NUM_GRAPHS 1024
#define F_DIM 512

// Workspace layout: A[g*8 + j] for j=0..6 = per-graph feature-dot sums,
// A[g*8 + 7] = node count for graph g. Total 1024*8 floats = 32 KB.

__global__ void zero_ws_kernel(float* __restrict__ A, int n) {
    int i = blockIdx.x * blockDim.x + threadIdx.x;
    if (i < n) A[i] = 0.0f;
}

// One wave per contiguous chunk of K<=64 sorted nodes. Lane l owns the
// contiguous float4s at features [4l,4l+4) and [256+4l,256+4l+4) — every
// wave-load is a full 1 KB contiguous segment (8 full 128B lines, vs the old
// stride-32B mapping's 16 half-lines). Hot loop accumulates RAW feature sums
// (8 v_add/row, not 56 FMA/row): (sum x)·W == sum(x·W), so the 7-way dot with
// W is applied only at segment flush (~1.26x per chunk). W lives in LDS, not
// 56 VGPRs -> hot live set ~45 VGPR -> 8 waves/SIMD, 32 waves/CU, 64 KB of
// loads in flight per CU. Grid 2048 blocks = exactly 8 blocks/CU.
__global__ __launch_bounds__(256, 8) void node_accum_kernel(
        const float* __restrict__ x, const int* __restrict__ batch,
        const float* __restrict__ W, float* __restrict__ A, int N) {
    __shared__ float Wl[7 * F_DIM];   // 14336 B

    // Stage W into LDS: 7*512 floats = 896 float4s across 256 threads.
    {
        const float4* Wv = (const float4*)W;
        float4* Wlv = (float4*)Wl;
        #pragma unroll
        for (int i = 0; i < 4; ++i) {
            int idx = threadIdx.x + i * 256;
            if (idx < 896) Wlv[idx] = Wv[idx];
        }
    }
    __syncthreads();

    const int lane = threadIdx.x & 63;
    const int wave = (blockIdx.x * blockDim.x + threadIdx.x) >> 6;
    const int num_waves = (gridDim.x * blockDim.x) >> 6;   // 8192
    const int K = (N + num_waves - 1) / num_waves;          // 13 for N=100000
    const int start = wave * K;
    const int len = min(N - start, K);
    if (len <= 0) return;

    // One coalesced load of the chunk's batch ids (lanes >= len clamp to last).
    int g_l = batch[start + min(lane, len - 1)];
    int g_prev = __shfl_up(g_l, 1, 64);
    unsigned long long bnd =
        __ballot(lane > 0 && lane < len && g_l != g_prev);  // start-of-new-segment lanes

    // x stream: depth-1 software pipeline over the WHOLE chunk (no restart at
    // segment boundaries; prefetched loads keep flying through the flush).
    const float* xb = x + (size_t)start * F_DIM + lane * 4;
    float4 a = ((const float4*)xb)[0];
    float4 c = *(const float4*)(xb + F_DIM / 2);

    float sa[8];
    #pragma unroll
    for (int k = 0; k < 8; ++k) sa[k] = 0.0f;
    int seg_start = 0;
    int g_cur = __shfl(g_l, 0, 64);

    for (int t = 0; t < len; ++t) {
        const float* xn = xb + (size_t)min(t + 1, len - 1) * F_DIM;
        float4 na = ((const float4*)xn)[0];
        float4 nc = *(const float4*)(xn + F_DIM / 2);

        sa[0] += a.x; sa[1] += a.y; sa[2] += a.z; sa[3] += a.w;
        sa[4] += c.x; sa[5] += c.y; sa[6] += c.z; sa[7] += c.w;

        // bnd is ballot-uniform -> this whole test/branch is scalar-pipe.
        bool bdry = (t + 1 == len) || ((bnd >> (t + 1)) & 1ULL);
        if (bdry) {
            // Flush segment [seg_start, t] for graph g_cur.
            const float4* wl = (const float4*)(Wl + lane * 4);
            float dot[7];
            #pragma unroll
            for (int j = 0; j < 7; ++j) {
                float4 w0 = wl[j * (F_DIM / 4)];        // Wl[j*512 + 4*lane]
                float4 w1 = wl[j * (F_DIM / 4) + 64];   // +256 floats
                dot[j] = sa[0] * w0.x + sa[1] * w0.y + sa[2] * w0.z + sa[3] * w0.w
                       + sa[4] * w1.x + sa[5] * w1.y + sa[6] * w1.z + sa[7] * w1.w;
            }
            #pragma unroll
            for (int j = 0; j < 7; ++j) {
                float v = dot[j];
                #pragma unroll
                for (int off = 32; off > 0; off >>= 1)
                    v += __shfl_down(v, off, 64);
                if (lane == 0) atomicAdd(A + g_cur * 8 + j, v);
            }
            if (lane == 0)
                atomicAdd(A + g_cur * 8 + 7, (float)(t + 1 - seg_start));
            #pragma unroll
            for (int k = 0; k < 8; ++k) sa[k] = 0.0f;
            seg_start = t + 1;
            if (t + 1 < len) g_cur = __shfl(g_l, t + 1, 64);
        }
        a = na; c = nc;
    }
}

__global__ void finalize_kernel(const float* __restrict__ A,
                                const float* __restrict__ b,
                                float* __restrict__ out) {
    int idx = blockIdx.x * blockDim.x + threadIdx.x;
    if (idx >= NUM_GRAPHS * 7) return;
    int g = idx / 7;
    int j = idx - g * 7;
    float cnt = A[g * 8 + 7];
    out[idx] = A[g * 8 + j] / fmaxf(cnt, 1.0f) + b[j];
}

extern "C" void kernel_launch(void* const* d_in, const int* in_sizes, int n_in,
                              void* d_out, int out_size, void* d_ws, size_t ws_size,
                              hipStream_t stream) {
    // Input order: x[100000,512] f32, edge_index (UNUSED), edge_attr (UNUSED),
    // batch_size[100000] int, W[7,512] f32, b[7] f32.
    const float* x     = (const float*)d_in[0];
    const int*   batch = (const int*)d_in[3];
    const float* W     = (const float*)d_in[4];
    const float* b     = (const float*)d_in[5];
    float* out = (float*)d_out;
    float* A   = (float*)d_ws;           // 1024*8 floats = 32 KB
    const int N = in_sizes[3];           // 100000 nodes

    const int ws_elems = NUM_GRAPHS * 8;
    zero_ws_kernel<<<(ws_elems + 255) / 256, 256, 0, stream>>>(A, ws_elems);

    // 2048 blocks * 256 thr = 8192 waves, 13 contiguous nodes per wave.
    // 8 blocks/CU (full residency at 8 waves/SIMD), 14.3 KB LDS/block.
    node_accum_kernel<<<2048, 256, 0, stream>>>(x, batch, W, A, N);

    finalize_kernel<<<(NUM_GRAPHS * 7 + 255) / 256, 256, 0, stream>>>(A, b, out);
}

// Round 3
// 331.093 us; speedup vs baseline: 1.2680x; 1.2680x over previous
//
#include <hip/hip_runtime.h>

#define NUM_GRAPHS 1024
#define F_DIM 512

// Workspace layout: A[g*8 + j] for j=0..6 = per-graph feature-dot sums,
// A[g*8 + 7] = node count for graph g. Total 1024*8 floats = 32 KB.

__global__ void zero_ws_kernel(float* __restrict__ A, int n) {
    int i = blockIdx.x * blockDim.x + threadIdx.x;
    if (i < n) A[i] = 0.0f;
}

// Flush one segment: dot the raw per-lane feature sums sa[8] with W rows
// (read straight from global; W is 14 KB and L1/L2-resident — flushes happen
// only ~2.3x per wave), wave-reduce, atomically accumulate, reset sa.
__device__ __forceinline__ void flush_segment(float (&sa)[8], int seg_len,
                                              int g, int lane,
                                              const float* __restrict__ W,
                                              float* __restrict__ A) {
    const float4* wl = (const float4*)(W + lane * 4);
    #pragma unroll
    for (int j = 0; j < 7; ++j) {
        float4 w0 = wl[j * (F_DIM / 4)];        // W[j][4*lane ..]
        float4 w1 = wl[j * (F_DIM / 4) + 64];   // W[j][256 + 4*lane ..]
        float v = sa[0] * w0.x + sa[1] * w0.y + sa[2] * w0.z + sa[3] * w0.w
                + sa[4] * w1.x + sa[5] * w1.y + sa[6] * w1.z + sa[7] * w1.w;
        #pragma unroll
        for (int off = 32; off > 0; off >>= 1)
            v += __shfl_down(v, off, 64);
        if (lane == 0) atomicAdd(A + g * 8 + j, v);
    }
    if (lane == 0) atomicAdd(A + g * 8 + 7, (float)seg_len);
    #pragma unroll
    for (int k = 0; k < 8; ++k) sa[k] = 0.0f;
}

// One wave per contiguous chunk of K<=64 sorted nodes. Lane l owns contiguous
// float4s at features [4l,4l+4) and [256+4l,+4) — every wave-load is a full
// 1 KB contiguous segment. Hot loop accumulates RAW feature sums (8 adds/row;
// (sum x)·W == sum(x·W)), W applied only at segment flush. Depth-2 software
// pipeline with STATICALLY-NAMED registers (runtime-indexed arrays spill —
// that was round 2's 235 MB scratch-writeback disaster under the forced
// launch_bounds(256,8) 32-VGPR budget). No occupancy forcing: ~64-80 VGPR ->
// 16 waves/CU, 2 KB in flight per wave = 32 KB/CU > Little's-law ~22 KB.
__global__ __launch_bounds__(256) void node_accum_kernel(
        const float* __restrict__ x, const int* __restrict__ batch,
        const float* __restrict__ W, float* __restrict__ A, int N) {
    const int lane = threadIdx.x & 63;
    const int wave = (blockIdx.x * blockDim.x + threadIdx.x) >> 6;
    const int num_waves = (gridDim.x * blockDim.x) >> 6;   // 8192
    const int K = (N + num_waves - 1) / num_waves;          // 13 for N=100000
    const int start = wave * K;
    const int len = min(N - start, K);
    if (len <= 0) return;

    // One coalesced load of the chunk's batch ids (lanes >= len clamp to last).
    int g_l = batch[start + min(lane, len - 1)];
    int g_prev = __shfl_up(g_l, 1, 64);
    unsigned long long bnd =
        __ballot(lane > 0 && lane < len && g_l != g_prev);  // start-of-new-segment lanes

    const float* xb = x + (size_t)start * F_DIM + lane * 4;

    // Depth-2 rolling prefetch, clamped at the last row (harmless L1 re-hit).
    const float* p1 = xb + (size_t)min(1, len - 1) * F_DIM;
    float4 a0 = ((const float4*)xb)[0];
    float4 c0 = *(const float4*)(xb + F_DIM / 2);
    float4 a1 = ((const float4*)p1)[0];
    float4 c1 = *(const float4*)(p1 + F_DIM / 2);

    float sa[8];
    #pragma unroll
    for (int k = 0; k < 8; ++k) sa[k] = 0.0f;
    int seg_start = 0;
    int g_cur = __shfl(g_l, 0, 64);

    for (int t = 0; t < len; t += 2) {
        const float* p2 = xb + (size_t)min(t + 2, len - 1) * F_DIM;
        float4 n0a = ((const float4*)p2)[0];
        float4 n0c = *(const float4*)(p2 + F_DIM / 2);

        sa[0] += a0.x; sa[1] += a0.y; sa[2] += a0.z; sa[3] += a0.w;
        sa[4] += c0.x; sa[5] += c0.y; sa[6] += c0.z; sa[7] += c0.w;
        // bnd is ballot-uniform -> scalar-pipe branch. || short-circuits so the
        // shift is never evaluated with t+1 == len (== 64 would be UB).
        if ((t + 1 == len) || ((bnd >> (t + 1)) & 1ULL)) {
            flush_segment(sa, t + 1 - seg_start, g_cur, lane, W, A);
            seg_start = t + 1;
            if (t + 1 < len) g_cur = __shfl(g_l, t + 1, 64);
        }

        const float* p3 = xb + (size_t)min(t + 3, len - 1) * F_DIM;
        float4 n1a = ((const float4*)p3)[0];
        float4 n1c = *(const float4*)(p3 + F_DIM / 2);

        if (t + 1 < len) {
            sa[0] += a1.x; sa[1] += a1.y; sa[2] += a1.z; sa[3] += a1.w;
            sa[4] += c1.x; sa[5] += c1.y; sa[6] += c1.z; sa[7] += c1.w;
            if ((t + 2 == len) || ((bnd >> (t + 2)) & 1ULL)) {
                flush_segment(sa, t + 2 - seg_start, g_cur, lane, W, A);
                seg_start = t + 2;
                if (t + 2 < len) g_cur = __shfl(g_l, t + 2, 64);
            }
        }
        a0 = n0a; c0 = n0c; a1 = n1a; c1 = n1c;
    }
}

__global__ void finalize_kernel(const float* __restrict__ A,
                                const float* __restrict__ b,
                                float* __restrict__ out) {
    int idx = blockIdx.x * blockDim.x + threadIdx.x;
    if (idx >= NUM_GRAPHS * 7) return;
    int g = idx / 7;
    int j = idx - g * 7;
    float cnt = A[g * 8 + 7];
    out[idx] = A[g * 8 + j] / fmaxf(cnt, 1.0f) + b[j];
}

extern "C" void kernel_launch(void* const* d_in, const int* in_sizes, int n_in,
                              void* d_out, int out_size, void* d_ws, size_t ws_size,
                              hipStream_t stream) {
    // Input order: x[100000,512] f32, edge_index (UNUSED), edge_attr (UNUSED),
    // batch_size[100000] int, W[7,512] f32, b[7] f32.
    const float* x     = (const float*)d_in[0];
    const int*   batch = (const int*)d_in[3];
    const float* W     = (const float*)d_in[4];
    const float* b     = (const float*)d_in[5];
    float* out = (float*)d_out;
    float* A   = (float*)d_ws;           // 1024*8 floats = 32 KB
    const int N = in_sizes[3];           // 100000 nodes

    const int ws_elems = NUM_GRAPHS * 8;
    zero_ws_kernel<<<(ws_elems + 255) / 256, 256, 0, stream>>>(A, ws_elems);

    // 2048 blocks * 256 thr = 8192 waves, 13 contiguous nodes per wave.
    node_accum_kernel<<<2048, 256, 0, stream>>>(x, batch, W, A, N);

    finalize_kernel<<<(NUM_GRAPHS * 7 + 255) / 256, 256, 0, stream>>>(A, b, out);
}